// Round 7
// baseline (74.583 us; speedup 1.0000x reference)
//
#include <hip/hip_runtime.h>
#include <math.h>

#define SM1 2047.0f

// ws float-index layout:
#define WS_D    0      // d[32] = exp(-p/2047)
#define WS_DW1  32     // d^(W+1)
#define WS_PF   64     // spectral filter
#define WS_RD   96     // 1/d = exp(+p/2047)
#define WS_DWW  128    // d^W
#define WS_DL   160    // d^64
#define WS_DEN  192    // 1-d (via expm1, accurate)
#define WS_P    224    // poles
#define WS_WIDX 256    // (int) W
#define WS_CTR  257    // (int) completion counter  (byte offset 1028, memset per call)
#define WS_WSUM 288    // wsum[32 k][32 o]  (1024)
#define WS_PART 1312   // partials[64 blk][32 c] (2048)
#define WS_XSUM 3360   // xsum[8][2048] (16384)
#define WS_YF   20480  // yF[8][2048][32] = F*scale      (524288)
#define WS_YB   544768 // yB[8][2048][32] = (B-x)*scale  (524288)

// K1: read x once -> xsum + per-block channel partials; LAST block (atomic
// counter) reduces partials -> xmean -> poles & all derived per-k constants.
__global__ __launch_bounds__(256) void k1(const float* __restrict__ x,
                                          const float* __restrict__ c_star,
                                          const float* __restrict__ dt,
                                          const float* __restrict__ lp,
                                          const float* __restrict__ pw,
                                          const float* __restrict__ pb,
                                          float* __restrict__ ws) {
    int blk = blockIdx.x, b = blk >> 3;
    int s = ((blk & 7) << 8) + threadIdx.x;
    __shared__ float pr[32][4];
    __shared__ int lastFlag;
    __shared__ float red2[8][32];
    __shared__ float xm[32];
    int lane = threadIdx.x & 63, wid = threadIdx.x >> 6;
    float acc = 0.f;
#pragma unroll
    for (int c = 0; c < 32; ++c) {
        float v = x[(size_t)(((b << 5) + c) << 11) + s];
        acc += v;
        float r = v;
        for (int off = 32; off; off >>= 1) r += __shfl_xor(r, off, 64);
        if (lane == 0) pr[c][wid] = r;
    }
    ws[WS_XSUM + (b << 11) + s] = acc;
    __syncthreads();
    if (threadIdx.x < 32) {
        float m = pr[threadIdx.x][0] + pr[threadIdx.x][1] + pr[threadIdx.x][2] + pr[threadIdx.x][3];
        ws[WS_PART + (blk << 5) + threadIdx.x] = m;
    }
    __threadfence();                       // release partials/xsum device-wide
    if (threadIdx.x == 0) {
        int v = atomicAdd((int*)ws + WS_CTR, 1);
        lastFlag = (v == 63);
    }
    __syncthreads();
    if (!lastFlag) return;
    __threadfence();                       // acquire other blocks' partials
    {
        int c = threadIdx.x & 31, g = threadIdx.x >> 5;
        float m = 0.f;
        for (int j = 0; j < 8; ++j) m += ws[WS_PART + (((g << 3) + j) << 5) + c];
        red2[g][c] = m;
    }
    __syncthreads();
    if (threadIdx.x < 32) {
        int k = threadIdx.x;
        float m = 0.f;
        for (int g = 0; g < 8; ++g) m += red2[g][k];
        xm[k] = m * (1.0f / 16384.0f);
    }
    __syncthreads();
    if (threadIdx.x < 32) {
        int k = threadIdx.x;
        float mc = c_star[0];
        for (int b2 = 1; b2 < 8; ++b2) mc = fmaxf(mc, c_star[b2]);
        float mdn = mc * dt[0];                         // CAUSAL_SAFETY = 1
        int W = (int)(mdn * SM1);
        while (W + 1 <= 2047 && (float)(W + 1) / SM1 <= mdn) ++W;
        while (W > 0 && (float)W / SM1 > mdn) --W;
        W = min(max(W, 0), 2047);
        if (k == 0) ((int*)ws)[WS_WIDX] = W;
        float accp = pb[k];
        for (int c = 0; c < 32; ++c) accp += xm[c] * pw[(c << 5) + k];
        float z = lp[k] + 0.1f * tanhf(accp);           // POLE_OFF_SCALE
        float p = log1pf(expf(z));                      // softplus
        p = fminf(fmaxf(p, 0.1f), 100.0f);
        ws[WS_P + k]   = p;
        ws[WS_D + k]   = expf(-p / SM1);
        ws[WS_DW1 + k] = expf(-p * (float)(W + 1) / SM1);
        float kn = (float)k / 31.0f;
        ws[WS_PF + k]  = expf(-4.0f * kn * kn);         // FILTER_STRENGTH
        ws[WS_RD + k]  = expf(p / SM1);
        ws[WS_DWW + k] = expf(-p * (float)W / SM1);
        ws[WS_DL + k]  = expf(-p * 64.0f / SM1);
        ws[WS_DEN + k] = -expm1f(-p / SM1);             // 1-d, accurate
    }
}

// K2: per-(b,dir) block: chunk scans (z in regs), LDS carry scan, fixup +
// inline scale (running-product powers), store yF / yB. Also writes wsum
// (redundant identical values across blocks).
__global__ __launch_bounds__(1024) void k2(const float* __restrict__ wla,
                                           const float* __restrict__ wph,
                                           float* __restrict__ ws) {
    __shared__ float xr[2048];
    __shared__ float carr[32][33];
    int tid = threadIdx.x;
    int b = blockIdx.x >> 1, dir = blockIdx.x & 1;
    for (int i = tid; i < 2048; i += 1024) xr[i] = ws[WS_XSUM + (b << 11) + i];
    int chunk = tid >> 5, k = tid & 31;
    float d  = ws[WS_D + k],   dw1 = ws[WS_DW1 + k], p  = ws[WS_P + k];
    float rd = ws[WS_RD + k],  dW  = ws[WS_DWW + k], dL = ws[WS_DL + k];
    float den = ws[WS_DEN + k], pf = ws[WS_PF + k];
    int W = ((const int*)ws)[WS_WIDX];
    __syncthreads();
    float z[64];
    float st = 0.f;
    if (dir == 0) {
        int t0 = chunk << 6;
#pragma unroll
        for (int i = 0; i < 64; ++i) {
            int t = t0 + i;
            float u = xr[t];
            int tl = t - W - 1;
            if (tl >= 0) u = fmaf(-dw1, xr[tl], u);
            st = fmaf(d, st, u);
            z[i] = st;
        }
    } else {
        int t1 = (chunk << 6) + 63;
#pragma unroll
        for (int i = 0; i < 64; ++i) {
            int t = t1 - i;
            float u = xr[t];
            int th = t + W + 1;
            if (th <= 2047) u = fmaf(-dw1, xr[th], u);
            st = fmaf(d, st, u);
            z[i] = st;
        }
    }
    // weighted inclusive Hillis-Steele over chunks: T = loc + dL * T_prev
    int sidx = (dir == 0) ? chunk : 31 - chunk;
    carr[sidx][k] = st;
    float m = dL, cur = st;
    for (int off = 1; off < 32; off <<= 1) {
        __syncthreads();
        float prev = (sidx >= off) ? carr[sidx - off][k] : 0.f;
        __syncthreads();
        cur = fmaf(m, prev, cur);
        carr[sidx][k] = cur;
        m = m * m;
    }
    __syncthreads();
    float cin = (sidx == 0) ? 0.f : carr[sidx - 1][k];
    float* yo = ws + ((dir == 0) ? WS_YF : WS_YB) + (((size_t)(b << 11)) << 5) + k;
    if (dir == 0) {
        int t0 = chunk << 6;
        float pwr = d;                                    // d^(i+1)
        float r1 = expf(-p * (float)t0 / SM1);            // d^t
        float r2 = expf(-p * (float)(2047 - t0) / SM1);   // d^(2047-t)
#pragma unroll
        for (int i = 0; i < 64; ++i) {
            int t = t0 + i;
            float g1 = d * (1.0f - fmaxf(r1, dW)) / den;  // d(1-d^min(W,t))/(1-d)
            float g2 = d * (1.0f - fmaxf(r2, dW)) / den;
            float sc = pf / (1.0f + g1 + g2);
            yo[(size_t)t << 5] = (z[i] + pwr * cin) * sc;
            pwr *= d; r1 *= d; r2 *= rd;
        }
    } else {
        int t1 = (chunk << 6) + 63;
        float pwr = d;                                    // d^(64-(t&63)) walking down
        float r1 = expf(-p * (float)t1 / SM1);
        float r2 = expf(-p * (float)(2047 - t1) / SM1);
#pragma unroll
        for (int i = 0; i < 64; ++i) {
            int t = t1 - i;
            float g1 = d * (1.0f - fmaxf(r1, dW)) / den;
            float g2 = d * (1.0f - fmaxf(r2, dW)) / den;
            float sc = pf / (1.0f + g1 + g2);
            yo[(size_t)t << 5] = (z[i] + pwr * cin - xr[t]) * sc;
            pwr *= d; r1 *= rd; r2 *= d;
        }
    }
    // wsum[k][o] (identical values from every block; visible to K3 at kernel boundary)
    {
        int kk = tid >> 5, o = tid & 31;
        float a = 0.f;
#pragma unroll 4
        for (int c = 0; c < 32; ++c) {
            int e = (((kk << 5) + c) << 5) | o;
            a += cosf(wph[e]) / (1.0f + expf(-wla[e]));
        }
        ws[WS_WSUM + tid] = a;
    }
}

// K3: y = yF + yB; out[b,o,t] = sum_k y[b,t,k] * wsum[k,o]
__global__ __launch_bounds__(1024) void k3(const float* __restrict__ ws,
                                           float* __restrict__ out) {
    __shared__ float wl[1024];
    __shared__ float yt[32 * 33];
    int tid = threadIdx.x;
    int b = blockIdx.x >> 6;
    int t0 = (blockIdx.x & 63) << 5;
    wl[tid] = ws[WS_WSUM + tid];
    {
        int tt = tid >> 5, k = tid & 31;
        size_t idx = (((size_t)((b << 11) + t0 + tt)) << 5) + k;
        yt[tt * 33 + k] = ws[WS_YF + idx] + ws[WS_YB + idx];
    }
    __syncthreads();
    {
        int o = tid >> 5, tt = tid & 31;
        float acc = 0.f;
#pragma unroll
        for (int k = 0; k < 32; ++k) acc = fmaf(yt[tt * 33 + k], wl[(k << 5) + o], acc);
        out[(((size_t)((b << 5) + o)) << 11) + t0 + tt] = acc;
    }
}

extern "C" void kernel_launch(void* const* d_in, const int* in_sizes, int n_in,
                              void* d_out, int out_size, void* d_ws, size_t ws_size,
                              hipStream_t stream) {
    const float* x      = (const float*)d_in[0];
    const float* c_star = (const float*)d_in[1];
    const float* dt     = (const float*)d_in[2];
    // d_in[3] = dx_star (unused)
    const float* wla    = (const float*)d_in[4];
    const float* wph    = (const float*)d_in[5];
    const float* lp     = (const float*)d_in[6];
    const float* pw     = (const float*)d_in[7];
    const float* pb     = (const float*)d_in[8];
    float* out = (float*)d_out;
    float* ws  = (float*)d_ws;

    hipMemsetAsync((char*)d_ws + WS_CTR * 4, 0, 4, stream);   // zero completion ctr
    k1<<<64,  256,  0, stream>>>(x, c_star, dt, lp, pw, pb, ws);
    k2<<<16,  1024, 0, stream>>>(wla, wph, ws);
    k3<<<512, 1024, 0, stream>>>(ws, out);
}

// Round 8
// 65.230 us; speedup vs baseline: 1.1434x; 1.1434x over previous
//
#include <hip/hip_runtime.h>
#include <math.h>

#define SM1 2047.0f
#define NBLK 64

// ws float-index layout:
#define WS_D     0       // d[32] = exp(-p/2047)
#define WS_DW1   32      // d^(W+1)
#define WS_PF    64      // spectral filter
#define WS_RD    96      // 1/d
#define WS_DWW   128     // d^W
#define WS_DL    160     // d^64
#define WS_DEN   192     // 1-d (expm1, accurate)
#define WS_P     224     // poles
#define WS_WIDX  256     // (int) W
#define WS_CNT   260     // (int) barrier arrive counter   (memset/call)
#define WS_GEN   261     // (int) barrier generation       (memset/call)
#define WS_WSUM  288     // wsum[32 k][32 o]               (1024)
#define WS_PCHAN 1312    // per-block channel sums [64][4] (256)
#define WS_PXS   2048    // partial xsum [8 b][8 ct][2048] (131072)
#define WS_XSUM  133120  // xsum[8][2048]                  (16384)
#define WS_YF    149504  // yF[8][2048][32]                (524288)
#define WS_YB    673792  // yB[8][2048][32]                (524288)
// top = 1198080 floats = 4.58 MiB

__device__ __forceinline__ void gridbar(int* cnt, int* gen) {
    __syncthreads();
    if (threadIdx.x == 0) {
        __threadfence();
        int g = __hip_atomic_load(gen, __ATOMIC_RELAXED, __HIP_MEMORY_SCOPE_AGENT);
        int a = __hip_atomic_fetch_add(cnt, 1, __ATOMIC_ACQ_REL, __HIP_MEMORY_SCOPE_AGENT);
        if (a == NBLK - 1) {
            __hip_atomic_store(cnt, 0, __ATOMIC_RELAXED, __HIP_MEMORY_SCOPE_AGENT);
            __hip_atomic_fetch_add(gen, 1, __ATOMIC_ACQ_REL, __HIP_MEMORY_SCOPE_AGENT);
        } else {
            while (__hip_atomic_load(gen, __ATOMIC_ACQUIRE, __HIP_MEMORY_SCOPE_AGENT) == g)
                __builtin_amdgcn_s_sleep(1);
        }
        __threadfence();
    }
    __syncthreads();
}

__global__ __launch_bounds__(1024) void fused(const float* __restrict__ x,
                                              const float* __restrict__ c_star,
                                              const float* __restrict__ dt,
                                              const float* __restrict__ lp,
                                              const float* __restrict__ pw,
                                              const float* __restrict__ pb,
                                              const float* __restrict__ wla,
                                              const float* __restrict__ wph,
                                              float* __restrict__ ws,
                                              float* __restrict__ out) {
    __shared__ float lds_xr[2048];
    __shared__ float lds_carr[32][33];
    __shared__ float lds_pr[16][4];
    __shared__ float lds_xm[32];
    __shared__ float lds_yt[32 * 33];
    __shared__ float lds_wl[1024];
    int tid = threadIdx.x, blk = blockIdx.x;
    int* cnt = (int*)ws + WS_CNT;
    int* gen = (int*)ws + WS_GEN;

    // ---- P1: read x once -> partial xsum + per-channel sums ----
    {
        int b = blk >> 3, ct = blk & 7;
        float a0 = 0.f, a1 = 0.f;
#pragma unroll
        for (int j = 0; j < 4; ++j) {
            int c = (ct << 2) + j;
            const float* xp = x + ((size_t)((b << 5) + c) << 11);
            float v0 = xp[tid], v1 = xp[tid + 1024];
            a0 += v0; a1 += v1;
            float r = v0 + v1;
            for (int off = 32; off; off >>= 1) r += __shfl_xor(r, off, 64);
            if ((tid & 63) == 0) lds_pr[tid >> 6][j] = r;
        }
        ws[WS_PXS + (((b << 3) + ct) << 11) + tid] = a0;
        ws[WS_PXS + (((b << 3) + ct) << 11) + tid + 1024] = a1;
        __syncthreads();
        if (tid < 4) {
            float m = 0.f;
            for (int w = 0; w < 16; ++w) m += lds_pr[w][tid];
            ws[WS_PCHAN + (blk << 2) + tid] = m;
        }
    }
    gridbar(cnt, gen);

    // ---- P1.5: xsum combine / prep / wsum ----
    if (blk < 16) {
        int g = (blk << 10) + tid;          // 0..16383
        int b = g >> 11, s = g & 2047;
        float m = 0.f;
#pragma unroll
        for (int ct = 0; ct < 8; ++ct) m += ws[WS_PXS + (((b << 3) + ct) << 11) + s];
        ws[WS_XSUM + (b << 11) + s] = m;
    } else if (blk == 16) {
        if (tid < 32) {
            int ct = tid >> 2, j = tid & 3;
            float m = 0.f;
            for (int b = 0; b < 8; ++b) m += ws[WS_PCHAN + (((b << 3) + ct) << 2) + j];
            lds_xm[tid] = m * (1.0f / 16384.0f);
        }
        __syncthreads();
        if (tid < 32) {
            int k = tid;
            float mc = c_star[0];
            for (int b2 = 1; b2 < 8; ++b2) mc = fmaxf(mc, c_star[b2]);
            float mdn = mc * dt[0];                         // CAUSAL_SAFETY = 1
            int W = (int)(mdn * SM1);
            while (W + 1 <= 2047 && (float)(W + 1) / SM1 <= mdn) ++W;
            while (W > 0 && (float)W / SM1 > mdn) --W;
            W = min(max(W, 0), 2047);
            if (k == 0) ((int*)ws)[WS_WIDX] = W;
            float accp = pb[k];
            for (int c = 0; c < 32; ++c) accp += lds_xm[c] * pw[(c << 5) + k];
            float z = lp[k] + 0.1f * tanhf(accp);           // POLE_OFF_SCALE
            float p = log1pf(expf(z));                      // softplus
            p = fminf(fmaxf(p, 0.1f), 100.0f);
            ws[WS_P + k]   = p;
            ws[WS_D + k]   = expf(-p / SM1);
            ws[WS_DW1 + k] = expf(-p * (float)(W + 1) / SM1);
            float kn = (float)k / 31.0f;
            ws[WS_PF + k]  = expf(-4.0f * kn * kn);         // FILTER_STRENGTH
            ws[WS_RD + k]  = expf(p / SM1);
            ws[WS_DWW + k] = expf(-p * (float)W / SM1);
            ws[WS_DL + k]  = expf(-p * 64.0f / SM1);
            ws[WS_DEN + k] = -expm1f(-p / SM1);
        }
    } else if (blk >= 17 && blk < 49) {
        int k = blk - 17;
        int o = tid >> 5, c = tid & 31;
        int e = (((k << 5) + c) << 5) + o;
        float v = cosf(wph[e]) / (1.0f + expf(-wla[e]));
        for (int off = 1; off < 32; off <<= 1) v += __shfl_xor(v, off, 32);
        if (c == 0) ws[WS_WSUM + (k << 5) + o] = v;
    }
    gridbar(cnt, gen);

    // ---- P2: scan (pass A: carries only) + LDS carry scan + pass B (rescan w/ carry, scaled) ----
    if (blk < 16) {
        int b = blk >> 1, dir = blk & 1;
        for (int i = tid; i < 2048; i += 1024) lds_xr[i] = ws[WS_XSUM + (b << 11) + i];
        int chunk = tid >> 5, k = tid & 31;
        float d  = ws[WS_D + k],   dw1 = ws[WS_DW1 + k], p   = ws[WS_P + k];
        float rd = ws[WS_RD + k],  dW  = ws[WS_DWW + k], dL  = ws[WS_DL + k];
        float den = ws[WS_DEN + k], pf = ws[WS_PF + k];
        float iden = d / den;
        int W = ((const int*)ws)[WS_WIDX];
        __syncthreads();
        float st = 0.f;
        if (dir == 0) {
            int t0 = chunk << 6;
#pragma unroll
            for (int i = 0; i < 64; ++i) {
                int t = t0 + i;
                float u = lds_xr[t];
                int tl = t - W - 1;
                if (tl >= 0) u = fmaf(-dw1, lds_xr[tl], u);
                st = fmaf(d, st, u);
            }
        } else {
            int t1 = (chunk << 6) + 63;
#pragma unroll
            for (int i = 0; i < 64; ++i) {
                int t = t1 - i;
                float u = lds_xr[t];
                int th = t + W + 1;
                if (th <= 2047) u = fmaf(-dw1, lds_xr[th], u);
                st = fmaf(d, st, u);
            }
        }
        // weighted inclusive Hillis-Steele over chunks: T = loc + dL * T_prev
        int sidx = (dir == 0) ? chunk : 31 - chunk;
        lds_carr[sidx][k] = st;
        float m = dL, cur = st;
        for (int off = 1; off < 32; off <<= 1) {
            __syncthreads();
            float prev = (sidx >= off) ? lds_carr[sidx - off][k] : 0.f;
            __syncthreads();
            cur = fmaf(m, prev, cur);
            lds_carr[sidx][k] = cur;
            m = m * m;
        }
        __syncthreads();
        float cin = (sidx == 0) ? 0.f : lds_carr[sidx - 1][k];
        // pass B: rescan with st seeded by cin == z_i + d^(i+1)*cin, scale inline
        float* yo = ws + ((dir == 0) ? WS_YF : WS_YB) + (((size_t)(b << 11)) << 5) + k;
        if (dir == 0) {
            int t0 = chunk << 6;
            float r1 = expf(-p * (float)t0 / SM1);            // d^t
            float r2 = expf(-p * (float)(2047 - t0) / SM1);   // d^(2047-t)
            st = cin;
#pragma unroll
            for (int i = 0; i < 64; ++i) {
                int t = t0 + i;
                float u = lds_xr[t];
                int tl = t - W - 1;
                if (tl >= 0) u = fmaf(-dw1, lds_xr[tl], u);
                st = fmaf(d, st, u);
                float g1 = iden * (1.0f - fmaxf(r1, dW));
                float g2 = iden * (1.0f - fmaxf(r2, dW));
                yo[(size_t)t << 5] = st * (pf / (1.0f + g1 + g2));
                r1 *= d; r2 *= rd;
            }
        } else {
            int t1 = (chunk << 6) + 63;
            float r1 = expf(-p * (float)t1 / SM1);
            float r2 = expf(-p * (float)(2047 - t1) / SM1);
            st = cin;
#pragma unroll
            for (int i = 0; i < 64; ++i) {
                int t = t1 - i;
                float u = lds_xr[t];
                int th = t + W + 1;
                if (th <= 2047) u = fmaf(-dw1, lds_xr[th], u);
                st = fmaf(d, st, u);
                float g1 = iden * (1.0f - fmaxf(r1, dW));
                float g2 = iden * (1.0f - fmaxf(r2, dW));
                yo[(size_t)t << 5] = (st - lds_xr[t]) * (pf / (1.0f + g1 + g2));
                r1 *= rd; r2 *= d;
            }
        }
    }
    gridbar(cnt, gen);

    // ---- P3: mix. 512 jobs over 64 blocks ----
    lds_wl[tid] = ws[WS_WSUM + tid];
    for (int j = 0; j < 8; ++j) {
        int job = (blk << 3) + j;
        int b = job >> 6, t0 = (job & 63) << 5;
        __syncthreads();
        {
            int tt = tid >> 5, k = tid & 31;
            size_t idx = ((size_t)((b << 11) + t0 + tt) << 5) + k;
            lds_yt[tt * 33 + k] = ws[WS_YF + idx] + ws[WS_YB + idx];
        }
        __syncthreads();
        {
            int o = tid >> 5, tt = tid & 31;
            float acc = 0.f;
#pragma unroll
            for (int kk = 0; kk < 32; ++kk)
                acc = fmaf(lds_yt[tt * 33 + kk], lds_wl[(kk << 5) + o], acc);
            out[((size_t)((b << 5) + o) << 11) + t0 + tt] = acc;
        }
    }
}

extern "C" void kernel_launch(void* const* d_in, const int* in_sizes, int n_in,
                              void* d_out, int out_size, void* d_ws, size_t ws_size,
                              hipStream_t stream) {
    const float* x      = (const float*)d_in[0];
    const float* c_star = (const float*)d_in[1];
    const float* dt     = (const float*)d_in[2];
    // d_in[3] = dx_star (unused)
    const float* wla    = (const float*)d_in[4];
    const float* wph    = (const float*)d_in[5];
    const float* lp     = (const float*)d_in[6];
    const float* pw     = (const float*)d_in[7];
    const float* pb     = (const float*)d_in[8];
    float* out = (float*)d_out;
    float* ws  = (float*)d_ws;

    hipMemsetAsync((char*)d_ws + WS_CNT * 4, 0, 8, stream);  // barrier cnt+gen
    fused<<<NBLK, 1024, 0, stream>>>(x, c_star, dt, lp, pw, pb, wla, wph, ws, out);
}

// Round 9
// 52.608 us; speedup vs baseline: 1.4177x; 1.2399x over previous
//
#include <hip/hip_runtime.h>
#include <math.h>

#define SM1 2047.0f

// ws float-index layout:
#define WS_D     0       // d[32] = exp(-p/2047)
#define WS_DW1   32      // d^(W+1)
#define WS_PF    64      // spectral filter
#define WS_RD    96      // 1/d
#define WS_DWW   128     // d^W
#define WS_DL    160     // d^64
#define WS_DEN   192     // 1-d (expm1, accurate)
#define WS_P     224     // poles
#define WS_WIDX  256     // (int) W
#define WS_CTR   260     // (int) completion counter (memset per call)
#define WS_WSUM  288     // wsum[32 k][32 o]          (1024)
#define WS_PART  1312    // channel partials [64][32] (2048)
#define WS_XSUM  3360    // xsum[8][2048]             (16384)
#define WS_YF    20480   // yF[8][2048][32]           (524288)
#define WS_YB    544768  // yB[8][2048][32]           (524288)

// K1: blocks 0-63: read x once -> xsum + per-block channel partials; LAST
// block (atomic counter) reduces partials -> xmean -> poles & derived
// constants. Blocks 64-67: wsum[k][o] concurrently.
__global__ __launch_bounds__(256) void k1(const float* __restrict__ x,
                                          const float* __restrict__ c_star,
                                          const float* __restrict__ dt,
                                          const float* __restrict__ lp,
                                          const float* __restrict__ pw,
                                          const float* __restrict__ pb,
                                          const float* __restrict__ wla,
                                          const float* __restrict__ wph,
                                          float* __restrict__ ws) {
    int blk = blockIdx.x, tid = threadIdx.x;
    if (blk >= 64) {                       // wsum blocks
        int k = ((blk - 64) << 3) + (tid >> 5);
        int o = tid & 31;
        float a = 0.f;
#pragma unroll 4
        for (int c = 0; c < 32; ++c) {
            int e = (((k << 5) + c) << 5) + o;
            a += cosf(wph[e]) / (1.0f + expf(-wla[e]));
        }
        ws[WS_WSUM + (k << 5) + o] = a;
        return;
    }
    int b = blk >> 3;
    int s = ((blk & 7) << 8) + tid;
    __shared__ float pr[32][4];
    __shared__ int lastFlag;
    __shared__ float red2[8][32];
    __shared__ float xm[32];
    int lane = tid & 63, wid = tid >> 6;
    float acc = 0.f;
#pragma unroll
    for (int c = 0; c < 32; ++c) {
        float v = x[(size_t)(((b << 5) + c) << 11) + s];
        acc += v;
        float r = v;
        for (int off = 32; off; off >>= 1) r += __shfl_xor(r, off, 64);
        if (lane == 0) pr[c][wid] = r;
    }
    ws[WS_XSUM + (b << 11) + s] = acc;
    __syncthreads();
    if (tid < 32) {
        float m = pr[tid][0] + pr[tid][1] + pr[tid][2] + pr[tid][3];
        ws[WS_PART + (blk << 5) + tid] = m;
    }
    __threadfence();
    if (tid == 0) {
        int v = atomicAdd((int*)ws + WS_CTR, 1);
        lastFlag = (v == 63);
    }
    __syncthreads();
    if (!lastFlag) return;
    __threadfence();
    {
        int c = tid & 31, g = tid >> 5;
        float m = 0.f;
        for (int j = 0; j < 8; ++j) m += ws[WS_PART + ((((g << 3) + j) << 5)) + c];
        red2[g][c] = m;
    }
    __syncthreads();
    if (tid < 32) {
        int k = tid;
        float m = 0.f;
        for (int g = 0; g < 8; ++g) m += red2[g][k];
        xm[k] = m * (1.0f / 16384.0f);
    }
    __syncthreads();
    if (tid < 32) {
        int k = tid;
        float mc = c_star[0];
        for (int b2 = 1; b2 < 8; ++b2) mc = fmaxf(mc, c_star[b2]);
        float mdn = mc * dt[0];                         // CAUSAL_SAFETY = 1
        int W = (int)(mdn * SM1);
        while (W + 1 <= 2047 && (float)(W + 1) / SM1 <= mdn) ++W;
        while (W > 0 && (float)W / SM1 > mdn) --W;
        W = min(max(W, 0), 2047);
        if (k == 0) ((int*)ws)[WS_WIDX] = W;
        float accp = pb[k];
        for (int c = 0; c < 32; ++c) accp += xm[c] * pw[(c << 5) + k];
        float z = lp[k] + 0.1f * tanhf(accp);           // POLE_OFF_SCALE
        float p = log1pf(expf(z));                      // softplus
        p = fminf(fmaxf(p, 0.1f), 100.0f);
        ws[WS_P + k]   = p;
        ws[WS_D + k]   = expf(-p / SM1);
        ws[WS_DW1 + k] = expf(-p * (float)(W + 1) / SM1);
        float kn = (float)k / 31.0f;
        ws[WS_PF + k]  = expf(-4.0f * kn * kn);         // FILTER_STRENGTH
        ws[WS_RD + k]  = expf(p / SM1);
        ws[WS_DWW + k] = expf(-p * (float)W / SM1);
        ws[WS_DL + k]  = expf(-p * 64.0f / SM1);
        ws[WS_DEN + k] = -expm1f(-p / SM1);
    }
}

// K2: per-(b,dir) block: pass A (carries only, no stores), LDS weighted
// Hillis-Steele, pass B rescan seeded with carry + inline scale -> yF/yB.
// No per-thread arrays -> no spill (VGPR ~48, verified in R8's fused P2).
__global__ __launch_bounds__(1024) void k2(float* __restrict__ ws) {
    __shared__ float xr[2048];
    __shared__ float carr[32][33];
    int tid = threadIdx.x;
    int b = blockIdx.x >> 1, dir = blockIdx.x & 1;
    for (int i = tid; i < 2048; i += 1024) xr[i] = ws[WS_XSUM + (b << 11) + i];
    int chunk = tid >> 5, k = tid & 31;
    float d  = ws[WS_D + k],   dw1 = ws[WS_DW1 + k], p   = ws[WS_P + k];
    float rd = ws[WS_RD + k],  dW  = ws[WS_DWW + k], dL  = ws[WS_DL + k];
    float den = ws[WS_DEN + k], pf = ws[WS_PF + k];
    float iden = d / den;
    int W = ((const int*)ws)[WS_WIDX];
    __syncthreads();
    float st = 0.f;
    if (dir == 0) {
        int t0 = chunk << 6;
#pragma unroll
        for (int i = 0; i < 64; ++i) {
            int t = t0 + i;
            float u = xr[t];
            int tl = t - W - 1;
            if (tl >= 0) u = fmaf(-dw1, xr[tl], u);
            st = fmaf(d, st, u);
        }
    } else {
        int t1 = (chunk << 6) + 63;
#pragma unroll
        for (int i = 0; i < 64; ++i) {
            int t = t1 - i;
            float u = xr[t];
            int th = t + W + 1;
            if (th <= 2047) u = fmaf(-dw1, xr[th], u);
            st = fmaf(d, st, u);
        }
    }
    // weighted inclusive Hillis-Steele over chunks: T = loc + dL * T_prev
    int sidx = (dir == 0) ? chunk : 31 - chunk;
    carr[sidx][k] = st;
    float m = dL, cur = st;
    for (int off = 1; off < 32; off <<= 1) {
        __syncthreads();
        float prev = (sidx >= off) ? carr[sidx - off][k] : 0.f;
        __syncthreads();
        cur = fmaf(m, prev, cur);
        carr[sidx][k] = cur;
        m = m * m;
    }
    __syncthreads();
    float cin = (sidx == 0) ? 0.f : carr[sidx - 1][k];
    // pass B: rescan with st seeded by cin (== z_i + d^(i+1)*cin), scale inline
    float* yo = ws + ((dir == 0) ? WS_YF : WS_YB) + (((size_t)(b << 11)) << 5) + k;
    if (dir == 0) {
        int t0 = chunk << 6;
        float r1 = expf(-p * (float)t0 / SM1);            // d^t
        float r2 = expf(-p * (float)(2047 - t0) / SM1);   // d^(2047-t)
        st = cin;
#pragma unroll
        for (int i = 0; i < 64; ++i) {
            int t = t0 + i;
            float u = xr[t];
            int tl = t - W - 1;
            if (tl >= 0) u = fmaf(-dw1, xr[tl], u);
            st = fmaf(d, st, u);
            float g1 = iden * (1.0f - fmaxf(r1, dW));
            float g2 = iden * (1.0f - fmaxf(r2, dW));
            yo[(size_t)t << 5] = st * (pf / (1.0f + g1 + g2));
            r1 *= d; r2 *= rd;
        }
    } else {
        int t1 = (chunk << 6) + 63;
        float r1 = expf(-p * (float)t1 / SM1);
        float r2 = expf(-p * (float)(2047 - t1) / SM1);
        st = cin;
#pragma unroll
        for (int i = 0; i < 64; ++i) {
            int t = t1 - i;
            float u = xr[t];
            int th = t + W + 1;
            if (th <= 2047) u = fmaf(-dw1, xr[th], u);
            st = fmaf(d, st, u);
            float g1 = iden * (1.0f - fmaxf(r1, dW));
            float g2 = iden * (1.0f - fmaxf(r2, dW));
            yo[(size_t)t << 5] = (st - xr[t]) * (pf / (1.0f + g1 + g2));
            r1 *= rd; r2 *= d;
        }
    }
}

// K3: y = yF + yB; out[b,o,t] = sum_k y[b,t,k] * wsum[k,o]
__global__ __launch_bounds__(1024) void k3(const float* __restrict__ ws,
                                           float* __restrict__ out) {
    __shared__ float wl[1024];
    __shared__ float yt[32 * 33];
    int tid = threadIdx.x;
    int b = blockIdx.x >> 6;
    int t0 = (blockIdx.x & 63) << 5;
    wl[tid] = ws[WS_WSUM + tid];
    {
        int tt = tid >> 5, k = tid & 31;
        size_t idx = ((size_t)((b << 11) + t0 + tt) << 5) + k;
        yt[tt * 33 + k] = ws[WS_YF + idx] + ws[WS_YB + idx];
    }
    __syncthreads();
    {
        int o = tid >> 5, tt = tid & 31;
        float acc = 0.f;
#pragma unroll
        for (int kk = 0; kk < 32; ++kk)
            acc = fmaf(yt[tt * 33 + kk], wl[(kk << 5) + o], acc);
        out[((size_t)((b << 5) + o) << 11) + t0 + tt] = acc;
    }
}

extern "C" void kernel_launch(void* const* d_in, const int* in_sizes, int n_in,
                              void* d_out, int out_size, void* d_ws, size_t ws_size,
                              hipStream_t stream) {
    const float* x      = (const float*)d_in[0];
    const float* c_star = (const float*)d_in[1];
    const float* dt     = (const float*)d_in[2];
    // d_in[3] = dx_star (unused)
    const float* wla    = (const float*)d_in[4];
    const float* wph    = (const float*)d_in[5];
    const float* lp     = (const float*)d_in[6];
    const float* pw     = (const float*)d_in[7];
    const float* pb     = (const float*)d_in[8];
    float* out = (float*)d_out;
    float* ws  = (float*)d_ws;

    hipMemsetAsync((char*)d_ws + WS_CTR * 4, 0, 4, stream);  // zero counter
    k1<<<68,  256,  0, stream>>>(x, c_star, dt, lp, pw, pb, wla, wph, ws);
    k2<<<16,  1024, 0, stream>>>(ws);
    k3<<<512, 1024, 0, stream>>>(ws, out);
}

// Round 10
// 42.825 us; speedup vs baseline: 1.7416x; 1.2284x over previous
//
#include <hip/hip_runtime.h>
#include <math.h>

#define SM1 2047.0f

// ws float-index layout:
#define WS_WSUM  288     // wsum[32 k][32 o]          (1024)
#define WS_PART  1312    // channel partials [64][32] (2048)
#define WS_XSUM  3360    // xsum[8][2048]             (16384)
#define WS_YF    20480   // yF[8][2048][32]           (524288)
#define WS_YB    544768  // yB[8][2048][32]           (524288)

// K1: blocks 0-63: read x once -> xsum + per-block channel partials.
//     blocks 64-67: wsum[k][o].  No atomics, no tail.
__global__ __launch_bounds__(256) void k1(const float* __restrict__ x,
                                          const float* __restrict__ wla,
                                          const float* __restrict__ wph,
                                          float* __restrict__ ws) {
    int blk = blockIdx.x, tid = threadIdx.x;
    if (blk >= 64) {                       // wsum blocks
        int k = ((blk - 64) << 3) + (tid >> 5);
        int o = tid & 31;
        float a = 0.f;
#pragma unroll 4
        for (int c = 0; c < 32; ++c) {
            int e = (((k << 5) + c) << 5) + o;
            a += cosf(wph[e]) / (1.0f + expf(-wla[e]));
        }
        ws[WS_WSUM + (k << 5) + o] = a;
        return;
    }
    int b = blk >> 3;
    int s = ((blk & 7) << 8) + tid;
    __shared__ float pr[32][4];
    int lane = tid & 63, wid = tid >> 6;
    float acc = 0.f;
#pragma unroll
    for (int c = 0; c < 32; ++c) {
        float v = x[(size_t)(((b << 5) + c) << 11) + s];
        acc += v;
        float r = v;
        for (int off = 32; off; off >>= 1) r += __shfl_xor(r, off, 64);
        if (lane == 0) pr[c][wid] = r;
    }
    ws[WS_XSUM + (b << 11) + s] = acc;
    __syncthreads();
    if (tid < 32) {
        float m = pr[tid][0] + pr[tid][1] + pr[tid][2] + pr[tid][3];
        ws[WS_PART + (blk << 5) + tid] = m;
    }
}

// K2: per-(b,dir) block. Redundant per-block prep (partials -> xmean -> poles
// -> derived constants in LDS), then: pass A (chunk carries, no stores), LDS
// weighted Hillis-Steele, pass B rescan seeded with carry + inline scale.
__global__ __launch_bounds__(1024) void k2(const float* __restrict__ c_star,
                                           const float* __restrict__ dt,
                                           const float* __restrict__ lp,
                                           const float* __restrict__ pw,
                                           const float* __restrict__ pb,
                                           float* __restrict__ ws) {
    __shared__ float xr[2048];
    __shared__ float carr[32][33];
    __shared__ float xm[32];
    __shared__ float cD[32], cDW1[32], cP[32], cRD[32], cDWW[32], cDL[32], cDEN[32], cPF[32];
    __shared__ int cWsh;
    int tid = threadIdx.x;
    int b = blockIdx.x >> 1, dir = blockIdx.x & 1;
    for (int i = tid; i < 2048; i += 1024) xr[i] = ws[WS_XSUM + (b << 11) + i];
    if (tid < 32) {
        float m = 0.f;
        for (int j = 0; j < 64; ++j) m += ws[WS_PART + (j << 5) + tid];
        xm[tid] = m * (1.0f / 16384.0f);
    }
    __syncthreads();
    if (tid < 32) {
        int k = tid;
        float mc = c_star[0];
        for (int b2 = 1; b2 < 8; ++b2) mc = fmaxf(mc, c_star[b2]);
        float mdn = mc * dt[0];                         // CAUSAL_SAFETY = 1
        int W = (int)(mdn * SM1);
        while (W + 1 <= 2047 && (float)(W + 1) / SM1 <= mdn) ++W;
        while (W > 0 && (float)W / SM1 > mdn) --W;
        W = min(max(W, 0), 2047);
        if (k == 0) cWsh = W;
        float accp = pb[k];
        for (int c = 0; c < 32; ++c) accp += xm[c] * pw[(c << 5) + k];
        float z = lp[k] + 0.1f * tanhf(accp);           // POLE_OFF_SCALE
        float p = log1pf(expf(z));                      // softplus
        p = fminf(fmaxf(p, 0.1f), 100.0f);
        cP[k]   = p;
        cD[k]   = expf(-p / SM1);
        cDW1[k] = expf(-p * (float)(W + 1) / SM1);
        float kn = (float)k / 31.0f;
        cPF[k]  = expf(-4.0f * kn * kn);                // FILTER_STRENGTH
        cRD[k]  = expf(p / SM1);
        cDWW[k] = expf(-p * (float)W / SM1);
        cDL[k]  = expf(-p * 64.0f / SM1);
        cDEN[k] = -expm1f(-p / SM1);
    }
    __syncthreads();
    int chunk = tid >> 5, k = tid & 31;
    float d  = cD[k],  dw1 = cDW1[k], p  = cP[k];
    float rd = cRD[k], dW  = cDWW[k], dL = cDL[k];
    float iden = d / cDEN[k], pf = cPF[k];
    int W = cWsh;
    float st = 0.f;
    if (dir == 0) {
        int t0 = chunk << 6;
#pragma unroll
        for (int i = 0; i < 64; ++i) {
            int t = t0 + i;
            float u = xr[t];
            int tl = t - W - 1;
            if (tl >= 0) u = fmaf(-dw1, xr[tl], u);
            st = fmaf(d, st, u);
        }
    } else {
        int t1 = (chunk << 6) + 63;
#pragma unroll
        for (int i = 0; i < 64; ++i) {
            int t = t1 - i;
            float u = xr[t];
            int th = t + W + 1;
            if (th <= 2047) u = fmaf(-dw1, xr[th], u);
            st = fmaf(d, st, u);
        }
    }
    // weighted inclusive Hillis-Steele over chunks: T = loc + dL * T_prev
    int sidx = (dir == 0) ? chunk : 31 - chunk;
    carr[sidx][k] = st;
    float m = dL, cur = st;
    for (int off = 1; off < 32; off <<= 1) {
        __syncthreads();
        float prev = (sidx >= off) ? carr[sidx - off][k] : 0.f;
        __syncthreads();
        cur = fmaf(m, prev, cur);
        carr[sidx][k] = cur;
        m = m * m;
    }
    __syncthreads();
    float cin = (sidx == 0) ? 0.f : carr[sidx - 1][k];
    // pass B: rescan seeded with cin (== z_i + d^(i+1)*cin), scale inline
    float* yo = ws + ((dir == 0) ? WS_YF : WS_YB) + (((size_t)(b << 11)) << 5) + k;
    if (dir == 0) {
        int t0 = chunk << 6;
        float r1 = expf(-p * (float)t0 / SM1);            // d^t
        float r2 = expf(-p * (float)(2047 - t0) / SM1);   // d^(2047-t)
        st = cin;
#pragma unroll
        for (int i = 0; i < 64; ++i) {
            int t = t0 + i;
            float u = xr[t];
            int tl = t - W - 1;
            if (tl >= 0) u = fmaf(-dw1, xr[tl], u);
            st = fmaf(d, st, u);
            float g1 = iden * (1.0f - fmaxf(r1, dW));
            float g2 = iden * (1.0f - fmaxf(r2, dW));
            yo[(size_t)t << 5] = st * (pf / (1.0f + g1 + g2));
            r1 *= d; r2 *= rd;
        }
    } else {
        int t1 = (chunk << 6) + 63;
        float r1 = expf(-p * (float)t1 / SM1);
        float r2 = expf(-p * (float)(2047 - t1) / SM1);
        st = cin;
#pragma unroll
        for (int i = 0; i < 64; ++i) {
            int t = t1 - i;
            float u = xr[t];
            int th = t + W + 1;
            if (th <= 2047) u = fmaf(-dw1, xr[th], u);
            st = fmaf(d, st, u);
            float g1 = iden * (1.0f - fmaxf(r1, dW));
            float g2 = iden * (1.0f - fmaxf(r2, dW));
            yo[(size_t)t << 5] = (st - xr[t]) * (pf / (1.0f + g1 + g2));
            r1 *= rd; r2 *= d;
        }
    }
}

// K3: y = yF + yB; out[b,o,t] = sum_k y[b,t,k] * wsum[k,o]
__global__ __launch_bounds__(1024) void k3(const float* __restrict__ ws,
                                           float* __restrict__ out) {
    __shared__ float wl[1024];
    __shared__ float yt[32 * 33];
    int tid = threadIdx.x;
    int b = blockIdx.x >> 6;
    int t0 = (blockIdx.x & 63) << 5;
    wl[tid] = ws[WS_WSUM + tid];
    {
        int tt = tid >> 5, k = tid & 31;
        size_t idx = ((size_t)((b << 11) + t0 + tt) << 5) + k;
        yt[tt * 33 + k] = ws[WS_YF + idx] + ws[WS_YB + idx];
    }
    __syncthreads();
    {
        int o = tid >> 5, tt = tid & 31;
        float acc = 0.f;
#pragma unroll
        for (int kk = 0; kk < 32; ++kk)
            acc = fmaf(yt[tt * 33 + kk], wl[(kk << 5) + o], acc);
        out[((size_t)((b << 5) + o) << 11) + t0 + tt] = acc;
    }
}

extern "C" void kernel_launch(void* const* d_in, const int* in_sizes, int n_in,
                              void* d_out, int out_size, void* d_ws, size_t ws_size,
                              hipStream_t stream) {
    const float* x      = (const float*)d_in[0];
    const float* c_star = (const float*)d_in[1];
    const float* dt     = (const float*)d_in[2];
    // d_in[3] = dx_star (unused)
    const float* wla    = (const float*)d_in[4];
    const float* wph    = (const float*)d_in[5];
    const float* lp     = (const float*)d_in[6];
    const float* pw     = (const float*)d_in[7];
    const float* pb     = (const float*)d_in[8];
    float* out = (float*)d_out;
    float* ws  = (float*)d_ws;

    k1<<<68,  256,  0, stream>>>(x, wla, wph, ws);
    k2<<<16,  1024, 0, stream>>>(c_star, dt, lp, pw, pb, ws);
    k3<<<512, 1024, 0, stream>>>(ws, out);
}

// Round 11
// 35.796 us; speedup vs baseline: 2.0836x; 1.1964x over previous
//
#include <hip/hip_runtime.h>
#include <math.h>

#define SM1 2047.0f

// ws float-index layout:
#define WS_WSUM  288     // wsum[32 k][32 o]            (1024)
#define WS_PART  1312    // channel partials [64][32]   (2048)
#define WS_XSUM  3360    // xsum[8][2048]               (16384)
#define WS_SCALE 20480   // scale[32 k][2048 t]         (65536)
#define WS_YF    90112   // yF[8][32 k][2048 t]         (524288)
#define WS_YB    614400  // yB[8][32 k][2048 t]         (524288)
// top = 1138688 floats = 4.34 MiB

// K1: blocks 0-63: read x once -> xsum + per-block channel partials.
//     blocks 64-67: wsum[k][o].  (proven in R9/R10)
__global__ __launch_bounds__(256) void k1(const float* __restrict__ x,
                                          const float* __restrict__ wla,
                                          const float* __restrict__ wph,
                                          float* __restrict__ ws) {
    int blk = blockIdx.x, tid = threadIdx.x;
    if (blk >= 64) {
        int k = ((blk - 64) << 3) + (tid >> 5);
        int o = tid & 31;
        float a = 0.f;
#pragma unroll 4
        for (int c = 0; c < 32; ++c) {
            int e = (((k << 5) + c) << 5) + o;
            a += cosf(wph[e]) / (1.0f + expf(-wla[e]));
        }
        ws[WS_WSUM + (k << 5) + o] = a;
        return;
    }
    int b = blk >> 3;
    int s = ((blk & 7) << 8) + tid;
    __shared__ float pr[32][4];
    int lane = tid & 63, wid = tid >> 6;
    float acc = 0.f;
#pragma unroll
    for (int c = 0; c < 32; ++c) {
        float v = x[(size_t)(((b << 5) + c) << 11) + s];
        acc += v;
        float r = v;
        for (int off = 32; off; off >>= 1) r += __shfl_xor(r, off, 64);
        if (lane == 0) pr[c][wid] = r;
    }
    ws[WS_XSUM + (b << 11) + s] = acc;
    __syncthreads();
    if (tid < 32) {
        float m = pr[tid][0] + pr[tid][1] + pr[tid][2] + pr[tid][3];
        ws[WS_PART + (blk << 5) + tid] = m;
    }
}

// Shared per-block prep: partials -> xmean -> poles -> derived consts in LDS.
__device__ __forceinline__ void prep(const float* __restrict__ c_star,
                                     const float* __restrict__ dt,
                                     const float* __restrict__ lp,
                                     const float* __restrict__ pw,
                                     const float* __restrict__ pb,
                                     const float* __restrict__ ws,
                                     float* xm, float* cP, float* cD, float* cDW1,
                                     float* cDL, float* cPF, float* cIDEN, int* cWsh) {
    int tid = threadIdx.x;
    if (tid < 32) {
        float m = 0.f;
        for (int j = 0; j < 64; ++j) m += ws[WS_PART + (j << 5) + tid];
        xm[tid] = m * (1.0f / 16384.0f);
    }
    __syncthreads();
    if (tid < 32) {
        int k = tid;
        float mc = c_star[0];
        for (int b2 = 1; b2 < 8; ++b2) mc = fmaxf(mc, c_star[b2]);
        float mdn = mc * dt[0];                         // CAUSAL_SAFETY = 1
        int W = (int)(mdn * SM1);
        while (W + 1 <= 2047 && (float)(W + 1) / SM1 <= mdn) ++W;
        while (W > 0 && (float)W / SM1 > mdn) --W;
        W = min(max(W, 0), 2047);
        if (k == 0) *cWsh = W;
        float accp = pb[k];
        for (int c = 0; c < 32; ++c) accp += xm[c] * pw[(c << 5) + k];
        float z = lp[k] + 0.1f * tanhf(accp);           // POLE_OFF_SCALE
        float p = log1pf(expf(z));                      // softplus
        p = fminf(fmaxf(p, 0.1f), 100.0f);
        float d = expf(-p / SM1);
        cP[k]   = p;
        cD[k]   = d;
        cDW1[k] = expf(-p * (float)(W + 1) / SM1);
        cDL[k]  = expf(-p * 64.0f / SM1);
        float kn = (float)k / 31.0f;
        cPF[k]  = expf(-4.0f * kn * kn);                // FILTER_STRENGTH
        cIDEN[k] = d / (-expm1f(-p / SM1));             // d/(1-d)
    }
    __syncthreads();
}

// K2: blocks 0-31: scan (b, dir, k-half); 512 thr = 32 chunks x 16 k.
//     blocks 32-47: scale table [k][t].
__global__ __launch_bounds__(512) void k2(const float* __restrict__ c_star,
                                          const float* __restrict__ dt,
                                          const float* __restrict__ lp,
                                          const float* __restrict__ pw,
                                          const float* __restrict__ pb,
                                          float* __restrict__ ws) {
    __shared__ float xr[2048];
    __shared__ float carr[32][17];
    __shared__ float xm[32], cP[32], cD[32], cDW1[32], cDL[32], cPF[32], cIDEN[32];
    __shared__ int cWsh;
    int tid = threadIdx.x, blk = blockIdx.x;
    prep(c_star, dt, lp, pw, pb, ws, xm, cP, cD, cDW1, cDL, cPF, cIDEN, &cWsh);
    int W = cWsh;

    if (blk >= 32) {                     // ---- scale-table blocks ----
        float rs = 1.0f / SM1;
#pragma unroll
        for (int j = 0; j < 8; ++j) {
            int gid = ((blk - 32) << 12) + (j << 9) + tid;   // [k][t]
            int k = gid >> 11, t = gid & 2047;
            float p = cP[k], iden = cIDEN[k];
            int n1 = min(W, t), n2 = min(W, 2047 - t);
            float g1 = -iden * expm1f(-p * (float)n1 * rs);
            float g2 = -iden * expm1f(-p * (float)n2 * rs);
            ws[WS_SCALE + gid] = cPF[k] / (1.0f + g1 + g2);
        }
        return;
    }
    // ---- scan blocks ----
    int b = blk >> 2, dir = (blk >> 1) & 1, kh = blk & 1;
    for (int i = tid; i < 2048; i += 512) xr[i] = ws[WS_XSUM + (b << 11) + i];
    int chunk = tid >> 4, kk = tid & 15;
    int k = (kh << 4) + kk;
    float d = cD[k], dw1 = cDW1[k], dL = cDL[k];
    __syncthreads();
    float st = 0.f;
    if (dir == 0) {
        int t0 = chunk << 6;
#pragma unroll
        for (int i = 0; i < 64; ++i) {
            int t = t0 + i;
            float u = xr[t];
            int tl = t - W - 1;
            if (tl >= 0) u = fmaf(-dw1, xr[tl], u);
            st = fmaf(d, st, u);
        }
    } else {
        int t1 = (chunk << 6) + 63;
#pragma unroll
        for (int i = 0; i < 64; ++i) {
            int t = t1 - i;
            float u = xr[t];
            int th = t + W + 1;
            if (th <= 2047) u = fmaf(-dw1, xr[th], u);
            st = fmaf(d, st, u);
        }
    }
    // weighted inclusive Hillis-Steele over chunks: T = loc + dL * T_prev
    int sidx = (dir == 0) ? chunk : 31 - chunk;
    carr[sidx][kk] = st;
    float m = dL, cur = st;
    for (int off = 1; off < 32; off <<= 1) {
        __syncthreads();
        float prev = (sidx >= off) ? carr[sidx - off][kk] : 0.f;
        __syncthreads();
        cur = fmaf(m, prev, cur);
        carr[sidx][kk] = cur;
        m = m * m;
    }
    __syncthreads();
    float cin = (sidx == 0) ? 0.f : carr[sidx - 1][kk];
    // pass B: rescan seeded with cin; raw values, float4-buffered stores
    float* yo = ws + ((dir == 0) ? WS_YF : WS_YB) + (((size_t)((b << 5) + k)) << 11);
    float4 v4;
    st = cin;
    if (dir == 0) {
        int t0 = chunk << 6;
#pragma unroll
        for (int i = 0; i < 64; ++i) {
            int t = t0 + i;
            float u = xr[t];
            int tl = t - W - 1;
            if (tl >= 0) u = fmaf(-dw1, xr[tl], u);
            st = fmaf(d, st, u);
            int ph = i & 3;
            if (ph == 0) v4.x = st; else if (ph == 1) v4.y = st;
            else if (ph == 2) v4.z = st;
            else { v4.w = st; *(float4*)(yo + (t & ~3)) = v4; }
        }
    } else {
        int t1 = (chunk << 6) + 63;
#pragma unroll
        for (int i = 0; i < 64; ++i) {
            int t = t1 - i;
            float u = xr[t];
            int th = t + W + 1;
            if (th <= 2047) u = fmaf(-dw1, xr[th], u);
            st = fmaf(d, st, u);
            float val = st - xr[t];
            int ph = t & 3;
            if (ph == 3) v4.w = val; else if (ph == 2) v4.z = val;
            else if (ph == 1) v4.y = val;
            else { v4.x = val; *(float4*)(yo + t) = v4; }
        }
    }
}

// K3: y = (yF + yB) * scale; out[b,o,t] = sum_k y[b,t,k] * wsum[k,o]
__global__ __launch_bounds__(1024) void k3(const float* __restrict__ ws,
                                           float* __restrict__ out) {
    __shared__ float wl[1024];
    __shared__ float yt[32 * 33];
    int tid = threadIdx.x;
    int b = blockIdx.x >> 6;
    int t0 = (blockIdx.x & 63) << 5;
    wl[tid] = ws[WS_WSUM + tid];
    {
        int k = tid >> 5, tt = tid & 31;
        size_t yi = (((size_t)((b << 5) + k)) << 11) + t0 + tt;
        float sc = ws[WS_SCALE + (k << 11) + t0 + tt];
        yt[tt * 33 + k] = (ws[WS_YF + yi] + ws[WS_YB + yi]) * sc;
    }
    __syncthreads();
    {
        int o = tid >> 5, tt = tid & 31;
        float acc = 0.f;
#pragma unroll
        for (int kk = 0; kk < 32; ++kk)
            acc = fmaf(yt[tt * 33 + kk], wl[(kk << 5) + o], acc);
        out[((size_t)((b << 5) + o) << 11) + t0 + tt] = acc;
    }
}

extern "C" void kernel_launch(void* const* d_in, const int* in_sizes, int n_in,
                              void* d_out, int out_size, void* d_ws, size_t ws_size,
                              hipStream_t stream) {
    const float* x      = (const float*)d_in[0];
    const float* c_star = (const float*)d_in[1];
    const float* dt     = (const float*)d_in[2];
    // d_in[3] = dx_star (unused)
    const float* wla    = (const float*)d_in[4];
    const float* wph    = (const float*)d_in[5];
    const float* lp     = (const float*)d_in[6];
    const float* pw     = (const float*)d_in[7];
    const float* pb     = (const float*)d_in[8];
    float* out = (float*)d_out;
    float* ws  = (float*)d_ws;

    k1<<<68,  256,  0, stream>>>(x, wla, wph, ws);
    k2<<<48,  512,  0, stream>>>(c_star, dt, lp, pw, pb, ws);
    k3<<<512, 1024, 0, stream>>>(ws, out);
}